// Round 4
// baseline (275.517 us; speedup 1.0000x reference)
//
#include <hip/hip_runtime.h>

#define FEAT 128
#define LAT  16
#define NB   256        // buckets = dst >> 8
#define NPB  256        // nodes per bucket
#define PAD  16         // ints between global counters (64B line each)
// edge packing: v = (src << 16) | dst   (n = 65536 -> both fit 16 bits)
// bucket = (v >> 8) & 255, local node = v & 255, src = (unsigned)v >> 16

// ---------- P1: bucket histogram over dst ----------
__global__ void k_bhist(const int* __restrict__ dst, int E, int* __restrict__ bcnt) {
    __shared__ int h[NB];
    int t = threadIdx.x;
    h[t] = 0;
    __syncthreads();
    int per = ((E + gridDim.x - 1) / gridDim.x + 3) & ~3;
    int e0 = blockIdx.x * per;
    int e1 = min(e0 + per, E);
    if (e0 < e1) {
        const int4* d4 = (const int4*)(dst + e0);
        int nq = (e1 - e0) >> 2;
        for (int q = t; q < nq; q += blockDim.x) {
            int4 v = d4[q];
            atomicAdd(&h[((unsigned)v.x) >> 8], 1);
            atomicAdd(&h[((unsigned)v.y) >> 8], 1);
            atomicAdd(&h[((unsigned)v.z) >> 8], 1);
            atomicAdd(&h[((unsigned)v.w) >> 8], 1);
        }
        for (int e = e0 + (nq << 2) + t; e < e1; e += blockDim.x)
            atomicAdd(&h[((unsigned)dst[e]) >> 8], 1);
    }
    __syncthreads();
    if (h[t]) atomicAdd(&bcnt[t * PAD], h[t]);
}

// ---------- tiny scan of 256 bucket counts ----------
__global__ void k_bscan(const int* __restrict__ bcnt, int* __restrict__ boff,
                        int* __restrict__ bcur) {
    __shared__ int s[NB];
    int t = threadIdx.x;
    s[t] = bcnt[t * PAD];
    __syncthreads();
    for (int off = 1; off < NB; off <<= 1) {
        int v = (t >= off) ? s[t - off] : 0;
        __syncthreads();
        s[t] += v;
        __syncthreads();
    }
    int excl = (t == 0) ? 0 : s[t - 1];
    boff[t] = excl;
    bcur[t * PAD] = excl;
    if (t == NB - 1) boff[NB] = s[t];
}

// ---------- P2: single-pass partition via LDS staging ----------
__global__ void k_part(const int* __restrict__ src, const int* __restrict__ dst, int E,
                       int* __restrict__ bcur, int* __restrict__ ebuf) {
    __shared__ int4 stage4[512];            // 2048 packed edges, 8 KB
    __shared__ int h[NB];
    __shared__ int lcur[NB];
    int* stage = (int*)stage4;
    int t = threadIdx.x;
    h[t] = 0;
    __syncthreads();
    int per = ((E + gridDim.x - 1) / gridDim.x + 3) & ~3;   // 2048 @ grid 1024
    int e0 = blockIdx.x * per;
    int e1 = min(e0 + per, E);
    int cnt = max(e1 - e0, 0);
    if (cnt > 0) {
        const int4* d4 = (const int4*)(dst + e0);
        const int4* s4 = (const int4*)(src + e0);
        int nq = cnt >> 2;
        for (int q = t; q < nq; q += 256) {
            int4 dv = d4[q];
            int4 sv = s4[q];
            atomicAdd(&h[((unsigned)dv.x) >> 8], 1);
            atomicAdd(&h[((unsigned)dv.y) >> 8], 1);
            atomicAdd(&h[((unsigned)dv.z) >> 8], 1);
            atomicAdd(&h[((unsigned)dv.w) >> 8], 1);
            stage4[q] = make_int4((sv.x << 16) | dv.x, (sv.y << 16) | dv.y,
                                  (sv.z << 16) | dv.z, (sv.w << 16) | dv.w);
        }
        for (int e = (nq << 2) + t; e < cnt; e += 256) {
            int d = dst[e0 + e], s = src[e0 + e];
            atomicAdd(&h[((unsigned)d) >> 8], 1);
            stage[e] = (s << 16) | d;
        }
    }
    __syncthreads();
    if (h[t]) lcur[t] = atomicAdd(&bcur[t * PAD], h[t]);
    __syncthreads();
    for (int e = t; e < cnt; e += 256) {
        int v = stage[e];
        int b = (v >> 8) & 255;                 // bucket = dst >> 8
        int pos = atomicAdd(&lcur[b], 1);
        ebuf[pos] = v;
    }
}

// ---------- per-node degree -> dinv, from bucketed edges ----------
__global__ void k_deg(const int* __restrict__ ebuf, const int* __restrict__ boff,
                      float* __restrict__ dinv) {
    __shared__ int h[NPB];
    int t = threadIdx.x;
    int b = blockIdx.x;
    h[t] = 0;
    __syncthreads();
    int e0 = boff[b], e1 = boff[b + 1];
    int e = e0 + t;
    for (; e + 768 < e1; e += 1024) {
        int v0 = ebuf[e], v1 = ebuf[e + 256], v2 = ebuf[e + 512], v3 = ebuf[e + 768];
        atomicAdd(&h[v0 & 255], 1);
        atomicAdd(&h[v1 & 255], 1);
        atomicAdd(&h[v2 & 255], 1);
        atomicAdd(&h[v3 & 255], 1);
    }
    for (; e < e1; e += 256) atomicAdd(&h[ebuf[e] & 255], 1);
    __syncthreads();
    dinv[b * NPB + t] = rsqrtf((float)(h[t] + 1));
}

// ---------- hs[i][:] = dinv[i] * (x[i] @ W1) ----------
__global__ void k_hs(const float* __restrict__ x, const float* __restrict__ W1,
                     const float* __restrict__ dinv, float* __restrict__ hs, int n) {
    __shared__ float w[FEAT * LAT];
    int t = threadIdx.x;
    for (int i = t; i < FEAT * LAT; i += blockDim.x) w[i] = W1[i];
    __syncthreads();
    int node = blockIdx.x * blockDim.x + t;
    if (node >= n) return;
    float acc[LAT];
#pragma unroll
    for (int j = 0; j < LAT; ++j) acc[j] = 0.f;
    const float4* xr = (const float4*)(x + (size_t)node * FEAT);
#pragma unroll 4
    for (int k4 = 0; k4 < FEAT / 4; ++k4) {
        float4 xv = xr[k4];
#pragma unroll
        for (int j = 0; j < LAT; ++j) {
            acc[j] += xv.x * w[(4 * k4 + 0) * LAT + j]
                    + xv.y * w[(4 * k4 + 1) * LAT + j]
                    + xv.z * w[(4 * k4 + 2) * LAT + j]
                    + xv.w * w[(4 * k4 + 3) * LAT + j];
        }
    }
    float dv = dinv[node];
    float4* o = (float4*)(hs + (size_t)node * LAT);
#pragma unroll
    for (int q = 0; q < 4; ++q) {
        float4 v;
        v.x = acc[4 * q + 0] * dv; v.y = acc[4 * q + 1] * dv;
        v.z = acc[4 * q + 2] * dv; v.w = acc[4 * q + 3] * dv;
        o[q] = v;
    }
}

// ---------- conv1: bucket-LDS aggregation + bias/relu/(·W2)/dinv ----------
__global__ __launch_bounds__(512) void k_conv1(const float* __restrict__ hs,
        const int* __restrict__ ebuf, const int* __restrict__ boff,
        const float* __restrict__ dinv, const float* __restrict__ b1,
        const float* __restrict__ W2, float* __restrict__ g) {
    __shared__ float acc[NPB * LAT];      // 16 KB
    int t = threadIdx.x;
    int b = blockIdx.x;
    const float4* hsv = (const float4*)(hs + (size_t)b * NPB * LAT);
    float4* accv = (float4*)acc;
    for (int i = t; i < NPB * LAT / 4; i += 512) accv[i] = hsv[i];  // self loop
    __syncthreads();
    int e0 = boff[b], e1 = boff[b + 1];
    int j = t & 15;
    int grp = t >> 4;                     // 0..31 edge groups
    int e = e0 + grp;
    for (; e + 96 < e1; e += 128) {
        int v0 = ebuf[e], v1 = ebuf[e + 32], v2 = ebuf[e + 64], v3 = ebuf[e + 96];
        float a0 = hs[(size_t)((unsigned)v0 >> 16) * LAT + j];
        float a1 = hs[(size_t)((unsigned)v1 >> 16) * LAT + j];
        float a2 = hs[(size_t)((unsigned)v2 >> 16) * LAT + j];
        float a3 = hs[(size_t)((unsigned)v3 >> 16) * LAT + j];
        atomicAdd(&acc[(v0 & 255) * LAT + j], a0);
        atomicAdd(&acc[(v1 & 255) * LAT + j], a1);
        atomicAdd(&acc[(v2 & 255) * LAT + j], a2);
        atomicAdd(&acc[(v3 & 255) * LAT + j], a3);
    }
    for (; e < e1; e += 32) {
        int v = ebuf[e];
        atomicAdd(&acc[(v & 255) * LAT + j], hs[(size_t)((unsigned)v >> 16) * LAT + j]);
    }
    __syncthreads();
    float w2j = W2[j];
    float b1j = b1[j];
#pragma unroll
    for (int p = 0; p < NPB / 32; ++p) {
        int nl = p * 32 + grp;
        int node = b * NPB + nl;
        float dv = dinv[node];
        float h1 = fmaxf(dv * acc[nl * LAT + j] + b1j, 0.f);
        float pp = h1 * w2j;
#pragma unroll
        for (int off = 8; off; off >>= 1) pp += __shfl_xor(pp, off, 16);
        if (j == 0) g[node] = dv * pp;
    }
}

// ---------- conv2: bucket-LDS scalar aggregation ----------
__global__ void k_conv2(const float* __restrict__ g, const int* __restrict__ ebuf,
                        const int* __restrict__ boff, const float* __restrict__ dinv,
                        const float* __restrict__ b2, float* __restrict__ out) {
    __shared__ float acc[NPB];
    int t = threadIdx.x;
    int b = blockIdx.x;
    acc[t] = g[b * NPB + t];              // self loop
    __syncthreads();
    int e0 = boff[b], e1 = boff[b + 1];
    int e = e0 + t;
    for (; e + 768 < e1; e += 1024) {
        int v0 = ebuf[e], v1 = ebuf[e + 256], v2 = ebuf[e + 512], v3 = ebuf[e + 768];
        float a0 = g[(unsigned)v0 >> 16], a1 = g[(unsigned)v1 >> 16];
        float a2 = g[(unsigned)v2 >> 16], a3 = g[(unsigned)v3 >> 16];
        atomicAdd(&acc[v0 & 255], a0);
        atomicAdd(&acc[v1 & 255], a1);
        atomicAdd(&acc[v2 & 255], a2);
        atomicAdd(&acc[v3 & 255], a3);
    }
    for (; e < e1; e += 256) {
        int v = ebuf[e];
        atomicAdd(&acc[v & 255], g[(unsigned)v >> 16]);
    }
    __syncthreads();
    out[b * NPB + t] = dinv[b * NPB + t] * acc[t] + b2[0];
}

extern "C" void kernel_launch(void* const* d_in, const int* in_sizes, int n_in,
                              void* d_out, int out_size, void* d_ws, size_t ws_size,
                              hipStream_t stream) {
    const float* x  = (const float*)d_in[0];
    const float* W1 = (const float*)d_in[1];
    const float* b1 = (const float*)d_in[2];
    const float* W2 = (const float*)d_in[3];
    const float* b2 = (const float*)d_in[4];
    const int*   ei = (const int*)d_in[5];

    int n = in_sizes[0] / FEAT;      // 65536 nodes
    int E = in_sizes[5] / 2;         // 2097152 edges
    const int* srcp = ei;
    const int* dstp = ei + E;

    // workspace layout (4-byte elements)
    int*   bcnt = (int*)d_ws;                        // NB*PAD
    int*   bcur = bcnt + NB * PAD;                   // NB*PAD
    int*   boff = bcur + NB * PAD;                   // NB+1 (pad 64)
    float* dinv = (float*)(boff + NB + 64);          // n
    float* hs   = dinv + n;                          // n*LAT
    float* g    = hs + (size_t)n * LAT;              // n
    int*   ebuf = (int*)(g + n);                     // E

    hipMemsetAsync(bcnt, 0, NB * PAD * sizeof(int), stream);

    k_bhist<<<1024, NB, 0, stream>>>(dstp, E, bcnt);
    k_bscan<<<1, NB, 0, stream>>>(bcnt, boff, bcur);
    k_part <<<1024, NB, 0, stream>>>(srcp, dstp, E, bcur, ebuf);
    k_deg  <<<NB, NPB, 0, stream>>>(ebuf, boff, dinv);
    k_hs   <<<(n + 255) / 256, 256, 0, stream>>>(x, W1, dinv, hs, n);
    k_conv1<<<NB, 512, 0, stream>>>(hs, ebuf, boff, dinv, b1, W2, g);
    k_conv2<<<NB, NPB, 0, stream>>>(g, ebuf, boff, dinv, b2, (float*)d_out);
}